// Round 3
// baseline (282.753 us; speedup 1.0000x reference)
//
#include <hip/hip_runtime.h>
#include <stdint.h>

typedef uint16_t u16;
typedef uint32_t u32;
typedef uint64_t u64;

#define CONF_THRESH 0.5f
#define PIOU_THRESH 0.5f
#define VCAP 192     // victim slots per box (in-degree <=128 verified R7/R8; out-degree symmetric)
#define NBIN 64      // fixed-width spatial bins (width 79.7; box width < 95 -> edges span <=1 bin)
#define DEPTH 8      // DMA pipeline depth (chunks in flight)
#define NSLOT 9      // ring slots (> DEPTH: no WAR on consumed slot)
#define SLOTU 1280   // u32 per slot: 256 meta + 4*256 victim

// ---------------------------------------------------------------------------
// K0: compact valid boxes (conf > 0.5).
// ---------------------------------------------------------------------------
__global__ void compact_kernel(const float* __restrict__ in, u32* __restrict__ Mctr,
                               u64* __restrict__ vkey, int N) {
    int i = blockIdx.x * 256 + threadIdx.x;
    if (i >= N) return;
    float c = in[(size_t)i * 5];
    if (c > CONF_THRESH) {
        u32 slot = atomicAdd(Mctr, 1u);
        vkey[slot] = ((u64)__float_as_uint(c) << 32) | (u64)(0xFFFFFFFFu - (u32)i);
    }
}

// ---------------------------------------------------------------------------
// K1: rank among valid via O(M^2) counting (key = conf_bits<<32 | ~idx).
// ---------------------------------------------------------------------------
__global__ void rankv_kernel(const u64* __restrict__ vkey, const u32* __restrict__ Mptr,
                             u32* __restrict__ rankv, int N) {
    __shared__ u64 keys[2048];
    int M = (int)*Mptr;
    int t = threadIdx.x;
    int i = blockIdx.x * 256 + t;
    int j0 = blockIdx.y * 2048;
    if (j0 >= M) return;
    if (blockIdx.x * 256 >= M) return;           // whole block inactive: skip staging
    for (int k = t; k < 2048; k += 256) {
        int j = j0 + k;
        keys[k] = (j < M) ? vkey[j] : 0ull;
    }
    __syncthreads();
    if (i >= M) return;
    u64 my = vkey[i];
    int cnt = 0;
    for (int k = 0; k < 2048; ++k) cnt += (keys[k] > my) ? 1 : 0;
    if (cnt) atomicAdd(&rankv[i], (u32)cnt);
}

// ---------------------------------------------------------------------------
// K2: scatter valid boxes into rank order + spatial bin append.
// ---------------------------------------------------------------------------
__global__ void scatterv_kernel(const float* __restrict__ in, const u64* __restrict__ vkey,
                                const u32* __restrict__ rankv, const u32* __restrict__ Mptr,
                                float4* __restrict__ sbox, u32* __restrict__ bcnt,
                                u16* __restrict__ blist, int N) {
    int s = blockIdx.x * 256 + threadIdx.x;
    int M = (int)*Mptr;
    if (s >= M) return;
    u32 idx = 0xFFFFFFFFu - (u32)(vkey[s] & 0xFFFFFFFFull);
    u32 r = rankv[s];
    const float* p = in + (size_t)idx * 5;
    float st = p[1], en = p[2], pk = p[3], h = p[4];
    sbox[r] = make_float4(st, en, pk, h);
    int bin = min(NBIN - 1, max(0, (int)(st * ((float)NBIN / 5100.0f))));
    u32 slot = atomicAdd(&bcnt[bin], 1u);
    if (slot < 256) blist[bin * 256 + slot] = (u16)r;
}

// ---------------------------------------------------------------------------
// K3: within-bin rank sort -> gidx-ordered geometry (sboxg) and rank (grankg;
// 0xFFFF marks empty slots). Spatial index for K4.
// ---------------------------------------------------------------------------
__global__ void bin_sort_kernel(const u32* __restrict__ bcnt, const u16* __restrict__ blist,
                                const float4* __restrict__ sbox,
                                float4* __restrict__ sboxg, u16* __restrict__ grankg) {
    __shared__ u16 rl[256];
    int bin = blockIdx.x, t = threadIdx.x;
    int n = min((int)bcnt[bin], 256);
    rl[t] = (t < n) ? blist[bin * 256 + t] : (u16)0xFFFF;
    __syncthreads();
    if (t < n) {
        u16 my = rl[t];
        int lr = 0;
        for (int q = 0; q < 256; ++q) lr += (rl[q] < my) ? 1 : 0;
        int g = bin * 256 + lr;
        grankg[g] = my;
        sboxg[g] = sbox[my];
    } else {
        grankg[bin * 256 + t] = (u16)0xFFFF;
    }
}

// ---------------------------------------------------------------------------
// K4: suppression edges, +-1-bin window (provably sufficient). Edge ri->rj
// (ri < rj in rank): same 64-rank chunk -> in-chunk mask bit in meta[rj];
// cross-chunk -> victim-list append on ri. meta[r] = {m_lo, m_hi, vcnt, pad}.
// ---------------------------------------------------------------------------
__global__ void mask_pm1_kernel(const float4* __restrict__ sboxg, const u16* __restrict__ grankg,
                                const u32* __restrict__ bcnt,
                                u32* __restrict__ meta, u16* __restrict__ vict) {
#pragma clang fp contract(off)
    __shared__ float4 cb[192];
    __shared__ u16 cr[192];
    int b = (int)blockIdx.x, s = (int)blockIdx.y, t = threadIdx.x;
    int w0 = (b - 1) * 256 + s * 192;            // window slice start (gidx)
    if (t < 192) {
        int g = w0 + t;
        bool ok = (g >= 0) && (g < NBIN * 256);
        cr[t] = ok ? grankg[g] : (u16)0xFFFF;
        cb[t] = ok ? sboxg[g] : make_float4(0.0f, 0.0f, 0.0f, 0.0f);
    }
    __syncthreads();
    int nb = min((int)bcnt[b], 256);
    int l = t;
    if (l >= nb) return;
    int g = b * 256 + l;
    int rj = (int)grankg[g];
    float4 bj = sboxg[g];
    float areaj = (bj.y - bj.x) * bj.w;
    for (int q = 0; q < 192; ++q) {
        int ri = (int)cr[q];
        if (ri >= rj) continue;                  // skips empties (0xFFFF) and self
        float4 bi = cb[q];
        float inter_start = fmaxf(bi.x, bj.x);
        float inter_end   = fminf(bi.y, bj.y);
        float inter_len   = fmaxf(inter_end - inter_start, 0.0f);
        float inter_h     = fminf(bi.w, bj.w);
        float inter_area  = inter_len * inter_h;
        float areai       = (bi.y - bi.x) * bi.w;
        float union_area  = areai + areaj - inter_area;
        float iou         = inter_area / union_area;
        float peak_dist   = fabsf(bi.z - bj.z);
        float union_start = fminf(bi.x, bj.x);
        float union_end   = fmaxf(bi.y, bj.y);
        float union_dist  = fabsf(union_end - union_start);
        float piou        = iou - peak_dist / union_dist;
        if (piou > PIOU_THRESH) {
            if ((ri >> 6) == (rj >> 6)) {
                atomicOr(&meta[rj * 4 + ((ri >> 5) & 1)], 1u << (ri & 31));
            } else {
                u32 slot = atomicAdd(&meta[ri * 4 + 2], 1u);
                if (slot < VCAP) vict[(size_t)ri * VCAP + slot] = (u16)rj;
            }
        }
    }
}

// ---------------------------------------------------------------------------
// K5: EXACT single-pass greedy NMS, scatter form, LDS-DMA pipelined.
// global_load_lds ring (9 slots x 5KB, depth 8) carries meta+victim lists;
// counted s_waitcnt vmcnt(40) keeps 8 chunks in flight (never drains).
// Uniform issue rate (dummy re-issues in tail) makes the literal correct for
// every iteration. Ballot fixpoint + LDS atomicAnd scatter as proven in R2.
// ---------------------------------------------------------------------------
__device__ __forceinline__ void gl16(const void* g, void* l) {
    __builtin_amdgcn_global_load_lds((const __attribute__((address_space(1))) u32*)g,
                                     (__attribute__((address_space(3))) u32*)l, 16, 0, 0);
}

__global__ void __launch_bounds__(64) nms_seq_kernel(
        const u32* __restrict__ meta, const u16* __restrict__ vict,
        const u32* __restrict__ Mptr, u32* __restrict__ keepf, int N) {
    __shared__ u32 alive[512];                   // 16384 bits, rank space
    __shared__ u32 ring[NSLOT * SLOTU];          // 45 KB DMA ring
    int lane = threadIdx.x;
    int M = (int)*Mptr;
    for (int q = lane; q < 512; q += 64) {
        int lo = q * 32;
        alive[q] = (M >= lo + 32) ? 0xFFFFFFFFu : ((M <= lo) ? 0u : ((1u << (M - lo)) - 1u));
    }
    __syncthreads();
    int nchunk = (M + 63) >> 6;
    if (nchunk == 0) {
        for (int q = lane; q < 512; q += 64) keepf[q] = 0u;
        return;
    }

#define ISSUE(c, sl) { \
    int rr = ((c) << 6) + lane; \
    u32* sb = &ring[(sl) * SLOTU]; \
    const u32* mg = meta + (size_t)rr * 4; \
    const u16* vg = vict + (size_t)rr * VCAP; \
    gl16(mg, sb); \
    gl16(vg,      sb + 256); \
    gl16(vg + 8,  sb + 512); \
    gl16(vg + 16, sb + 768); \
    gl16(vg + 24, sb + 1024); }

#define VSC(w, k) { \
    if ((int)(k) < nv)     { int tg = (int)((w) & 0xFFFFu); atomicAnd(&alive[tg >> 5], ~(1u << (tg & 31))); } \
    if ((int)(k) + 1 < nv) { int tg = (int)((w) >> 16);     atomicAnd(&alive[tg >> 5], ~(1u << (tg & 31))); } }

    // prologue: fill pipe (dummy chunk 0 if nchunk < DEPTH keeps count uniform)
    for (int k = 0; k < DEPTH; ++k) { int cc = (k < nchunk) ? k : 0; ISSUE(cc, k); }
    int slot = 0, islot = DEPTH;                 // next consume / next issue slot

    for (int c = 0; c < nchunk; ++c) {
        int cn = c + DEPTH; if (cn >= nchunk) cn = 0;   // dummy keeps vmcnt math exact
        ISSUE(cn, islot);
        islot++; if (islot == NSLOT) islot = 0;

        asm volatile("s_waitcnt vmcnt(40)" ::: "memory");   // 8 chunks x 5 loads stay in flight
        __builtin_amdgcn_sched_barrier(0);

        int base = c << 6;
        const u32* sb = &ring[slot * SLOTU];
        uint4 MT = ((const uint4*)sb)[lane];
        u64 m = ((u64)MT.y << 32) | (u64)MT.x;
        int vc = min((int)MT.z, VCAP);
        u64 av = ((u64)alive[(base >> 5) + 1] << 32) | (u64)alive[base >> 5];
        u64 undec = av;
        u64 kept = 0ull;
        while (undec) {
            bool iam = (undec >> lane) & 1ull;
            bool bad = (m & kept) != 0ull;
            bool rdy = (m & undec) == 0ull;
            u64 newk = __ballot(iam && !bad && rdy);
            u64 newr = __ballot(iam && bad);
            kept |= newk;
            undec &= ~(newk | newr);
        }
        if (lane < 2) alive[(base >> 5) + lane] = (u32)(kept >> (lane * 32));
        int nv = ((kept >> lane) & 1ull) ? vc : 0;
        if (__ballot(nv > 0)) {
            uint4 V0 = ((const uint4*)(sb + 256))[lane];
            uint4 V1 = ((const uint4*)(sb + 512))[lane];
            VSC(V0.x, 0)  VSC(V0.y, 2)  VSC(V0.z, 4)  VSC(V0.w, 6)
            VSC(V1.x, 8)  VSC(V1.y, 10) VSC(V1.z, 12) VSC(V1.w, 14)
            if (__ballot(nv > 16)) {
                uint4 V2 = ((const uint4*)(sb + 768))[lane];
                uint4 V3 = ((const uint4*)(sb + 1024))[lane];
                VSC(V2.x, 16) VSC(V2.y, 18) VSC(V2.z, 20) VSC(V2.w, 22)
                VSC(V3.x, 24) VSC(V3.y, 26) VSC(V3.z, 28) VSC(V3.w, 30)
            }
            if (__ballot(nv > 32)) {
                int r = base + lane;
                for (int e = 32; e < nv; ++e) {
                    int tg = (int)vict[(size_t)r * VCAP + e];
                    atomicAnd(&alive[tg >> 5], ~(1u << (tg & 31)));
                }
            }
        }
        slot++; if (slot == NSLOT) slot = 0;
    }

    for (int q = lane; q < 512; q += 64) keepf[q] = alive[q];
#undef ISSUE
#undef VSC
}

// ---------------------------------------------------------------------------
// K6: out[r] = sorted geometry * keep bit (rank space); rows >= M exact zeros.
// ---------------------------------------------------------------------------
__global__ void out_kernel(const float4* __restrict__ sbox, const u32* __restrict__ keepf,
                           const u32* __restrict__ Mptr, float4* __restrict__ out, int N) {
    int r = blockIdx.x * 256 + threadIdx.x;
    if (r >= N) return;
    int M = (int)*Mptr;
    if (r < M) {
        float k = (float)((keepf[r >> 5] >> (r & 31)) & 1u);
        float4 v = sbox[r];
        out[r] = make_float4(v.x * k, v.y * k, v.z * k, v.w * k);
    } else {
        out[r] = make_float4(0.0f, 0.0f, 0.0f, 0.0f);
    }
}

// ---------------------------------------------------------------------------
extern "C" void kernel_launch(void* const* d_in, const int* in_sizes, int n_in,
                              void* d_out, int out_size, void* d_ws, size_t ws_size,
                              hipStream_t stream) {
    const float* in = (const float*)d_in[0];
    int N = in_sizes[0] / 5;          // 16384

    char* ws = (char*)d_ws;
    size_t off = 0;
    // ---- zeroed region (one memset) ----
    u32* rankv   = (u32*)(ws + off); off += (size_t)N * 4;            // 64 KB
    u32* Mctr    = (u32*)(ws + off); off += 16;
    u32* bcnt    = (u32*)(ws + off); off += (size_t)NBIN * 4;         // 256 B
    u32* meta    = (u32*)(ws + off); off += (size_t)N * 16;           // 256 KB {m_lo,m_hi,vcnt,pad}
    size_t zbytes = off;
    // ---- non-zeroed ----
    float4* sbox  = (float4*)(ws + off); off += (size_t)N * 16;       // 256 KB
    float4* sboxg = (float4*)(ws + off); off += (size_t)N * 16;       // 256 KB
    u64* vkey    = (u64*)(ws + off);  off += (size_t)N * 8;           // 128 KB
    u16* vict    = (u16*)(ws + off);  off += (size_t)N * VCAP * 2;    // 6 MB (16B-aligned)
    u16* blist   = (u16*)(ws + off);  off += (size_t)NBIN * 256 * 2;  // 32 KB
    u16* grankg  = (u16*)(ws + off);  off += (size_t)N * 2;           // 32 KB
    u32* keepf   = (u32*)(ws + off);  off += 512 * 4;                 // 2 KB

    hipMemsetAsync(rankv, 0, zbytes, stream);

    compact_kernel<<<N / 256, 256, 0, stream>>>(in, Mctr, vkey, N);
    rankv_kernel<<<dim3(N / 256, N / 2048), 256, 0, stream>>>(vkey, Mctr, rankv, N);
    scatterv_kernel<<<N / 256, 256, 0, stream>>>(in, vkey, rankv, Mctr, sbox, bcnt, blist, N);
    bin_sort_kernel<<<NBIN, 256, 0, stream>>>(bcnt, blist, sbox, sboxg, grankg);
    mask_pm1_kernel<<<dim3(NBIN, 4), 256, 0, stream>>>(sboxg, grankg, bcnt, meta, vict);
    nms_seq_kernel<<<1, 64, 0, stream>>>(meta, vict, Mctr, keepf, N);
    out_kernel<<<N / 256, 256, 0, stream>>>(sbox, keepf, Mctr, (float4*)d_out, N);
}

// Round 6
// 246.249 us; speedup vs baseline: 1.1482x; 1.1482x over previous
//
#include <hip/hip_runtime.h>
#include <stdint.h>

typedef uint16_t u16;
typedef uint32_t u32;
typedef uint64_t u64;

#define CONF_THRESH 0.5f
#define PIOU_THRESH 0.5f
#define VCAP 192     // victim slots per box (in-degree <=128 verified R7/R8; out-degree symmetric)
#define NBIN 64      // fixed-width spatial bins (width 79.7; box width < 95 -> edges span <=1 bin)
#define NWAVE 8      // turn-passing waves in the NMS kernel

// ---------------------------------------------------------------------------
// K0: compact valid boxes (conf > 0.5).
// ---------------------------------------------------------------------------
__global__ void compact_kernel(const float* __restrict__ in, u32* __restrict__ Mctr,
                               u64* __restrict__ vkey, int N) {
    int i = blockIdx.x * 256 + threadIdx.x;
    if (i >= N) return;
    float c = in[(size_t)i * 5];
    if (c > CONF_THRESH) {
        u32 slot = atomicAdd(Mctr, 1u);
        vkey[slot] = ((u64)__float_as_uint(c) << 32) | (u64)(0xFFFFFFFFu - (u32)i);
    }
}

// ---------------------------------------------------------------------------
// K1: rank among valid via O(M^2) counting (key = conf_bits<<32 | ~idx).
// ---------------------------------------------------------------------------
__global__ void rankv_kernel(const u64* __restrict__ vkey, const u32* __restrict__ Mptr,
                             u32* __restrict__ rankv, int N) {
    __shared__ u64 keys[2048];
    int M = (int)*Mptr;
    int t = threadIdx.x;
    int i = blockIdx.x * 256 + t;
    int j0 = blockIdx.y * 2048;
    if (j0 >= M) return;
    if (blockIdx.x * 256 >= M) return;           // whole block inactive: skip staging
    for (int k = t; k < 2048; k += 256) {
        int j = j0 + k;
        keys[k] = (j < M) ? vkey[j] : 0ull;
    }
    __syncthreads();
    if (i >= M) return;
    u64 my = vkey[i];
    int cnt = 0;
    for (int k = 0; k < 2048; ++k) cnt += (keys[k] > my) ? 1 : 0;
    if (cnt) atomicAdd(&rankv[i], (u32)cnt);
}

// ---------------------------------------------------------------------------
// K2: scatter valid boxes into rank order + spatial bin append.
// ---------------------------------------------------------------------------
__global__ void scatterv_kernel(const float* __restrict__ in, const u64* __restrict__ vkey,
                                const u32* __restrict__ rankv, const u32* __restrict__ Mptr,
                                float4* __restrict__ sbox, u32* __restrict__ bcnt,
                                u16* __restrict__ blist, int N) {
    int s = blockIdx.x * 256 + threadIdx.x;
    int M = (int)*Mptr;
    if (s >= M) return;
    u32 idx = 0xFFFFFFFFu - (u32)(vkey[s] & 0xFFFFFFFFull);
    u32 r = rankv[s];
    const float* p = in + (size_t)idx * 5;
    float st = p[1], en = p[2], pk = p[3], h = p[4];
    sbox[r] = make_float4(st, en, pk, h);
    int bin = min(NBIN - 1, max(0, (int)(st * ((float)NBIN / 5100.0f))));
    u32 slot = atomicAdd(&bcnt[bin], 1u);
    if (slot < 256) blist[bin * 256 + slot] = (u16)r;
}

// ---------------------------------------------------------------------------
// K3: within-bin rank sort -> gidx-ordered geometry (sboxg) and rank (grankg;
// 0xFFFF marks empty slots). Spatial index for K4.
// ---------------------------------------------------------------------------
__global__ void bin_sort_kernel(const u32* __restrict__ bcnt, const u16* __restrict__ blist,
                                const float4* __restrict__ sbox,
                                float4* __restrict__ sboxg, u16* __restrict__ grankg) {
    __shared__ u16 rl[256];
    int bin = blockIdx.x, t = threadIdx.x;
    int n = min((int)bcnt[bin], 256);
    rl[t] = (t < n) ? blist[bin * 256 + t] : (u16)0xFFFF;
    __syncthreads();
    if (t < n) {
        u16 my = rl[t];
        int lr = 0;
        for (int q = 0; q < 256; ++q) lr += (rl[q] < my) ? 1 : 0;
        int g = bin * 256 + lr;
        grankg[g] = my;
        sboxg[g] = sbox[my];
    } else {
        grankg[bin * 256 + t] = (u16)0xFFFF;
    }
}

// ---------------------------------------------------------------------------
// K4: suppression edges, +-1-bin window (provably sufficient). Edge ri->rj
// (ri < rj in rank): same 64-rank chunk -> in-chunk mask bit in meta[rj];
// cross-chunk -> victim-list append on ri. meta[r] = {m_lo, m_hi, vcnt, pad}.
// ---------------------------------------------------------------------------
__global__ void mask_pm1_kernel(const float4* __restrict__ sboxg, const u16* __restrict__ grankg,
                                const u32* __restrict__ bcnt,
                                u32* __restrict__ meta, u16* __restrict__ vict) {
#pragma clang fp contract(off)
    __shared__ float4 cb[192];
    __shared__ u16 cr[192];
    int b = (int)blockIdx.x, s = (int)blockIdx.y, t = threadIdx.x;
    int w0 = (b - 1) * 256 + s * 192;            // window slice start (gidx)
    if (t < 192) {
        int g = w0 + t;
        bool ok = (g >= 0) && (g < NBIN * 256);
        cr[t] = ok ? grankg[g] : (u16)0xFFFF;
        cb[t] = ok ? sboxg[g] : make_float4(0.0f, 0.0f, 0.0f, 0.0f);
    }
    __syncthreads();
    int nb = min((int)bcnt[b], 256);
    int l = t;
    if (l >= nb) return;
    int g = b * 256 + l;
    int rj = (int)grankg[g];
    float4 bj = sboxg[g];
    float areaj = (bj.y - bj.x) * bj.w;
    for (int q = 0; q < 192; ++q) {
        int ri = (int)cr[q];
        if (ri >= rj) continue;                  // skips empties (0xFFFF) and self
        float4 bi = cb[q];
        float inter_start = fmaxf(bi.x, bj.x);
        float inter_end   = fminf(bi.y, bj.y);
        float inter_len   = fmaxf(inter_end - inter_start, 0.0f);
        float inter_h     = fminf(bi.w, bj.w);
        float inter_area  = inter_len * inter_h;
        float areai       = (bi.y - bi.x) * bi.w;
        float union_area  = areai + areaj - inter_area;
        float iou         = inter_area / union_area;
        float peak_dist   = fabsf(bi.z - bj.z);
        float union_start = fminf(bi.x, bj.x);
        float union_end   = fmaxf(bi.y, bj.y);
        float union_dist  = fabsf(union_end - union_start);
        float piou        = iou - peak_dist / union_dist;
        if (piou > PIOU_THRESH) {
            if ((ri >> 6) == (rj >> 6)) {
                atomicOr(&meta[rj * 4 + ((ri >> 5) & 1)], 1u << (ri & 31));
            } else {
                u32 slot = atomicAdd(&meta[ri * 4 + 2], 1u);
                if (slot < VCAP) vict[(size_t)ri * VCAP + slot] = (u16)rj;
            }
        }
    }
}

// ---------------------------------------------------------------------------
// K5: EXACT greedy NMS via 8-wave TURN-PASSING (no asm, no model risk).
// Wave w owns chunks w, w+8, ... Per round: all 8 waves load their chunk's
// meta + 32 victims with plain C loads; __syncthreads() (its mandatory
// vmcnt-drain forces prefetch completion -- compiler cannot defeat this);
// then waves execute chunks in rank order via LDS acquire/release turn
// counter. Per turn: alive read -> proven ballot fixpoint -> victim scatter
// (registers only). Load latency amortized once per round, 8-wide.
// Turn induction: rounds < last are full, so turn reaches (rd+1)*8; barriers
// are uniform (nround uniform) -> no deadlock. Fixpoint masks are lower-
// triangular by construction (bit ri-base < rj-base), so the forced-progress
// guard is dead code on any data K4 can produce (kept as hang insurance).
// ---------------------------------------------------------------------------
__global__ void __launch_bounds__(NWAVE * 64) nms_seq_kernel(
        const u32* __restrict__ meta, const u16* __restrict__ vict,
        const u32* __restrict__ Mptr, u32* __restrict__ keepf, int N) {
    __shared__ u32 alive[512];                   // 16384 bits, rank space
    __shared__ u32 turnv;
    int tid = threadIdx.x;
    int w = tid >> 6, lane = tid & 63;
    int M = (int)*Mptr;
    for (int q = tid; q < 512; q += NWAVE * 64) {
        int lo = q * 32;
        alive[q] = (M >= lo + 32) ? 0xFFFFFFFFu : ((M <= lo) ? 0u : ((1u << (M - lo)) - 1u));
    }
    if (tid == 0) turnv = 0u;
    __syncthreads();
    int nchunk = (M + 63) >> 6;
    int nround = (nchunk + NWAVE - 1) / NWAVE;

    for (int rd = 0; rd < nround; ++rd) {
        int c = rd * NWAVE + w;
        bool act = (c < nchunk);
        uint4 MT = make_uint4(0, 0, 0, 0);
        uint4 V0 = MT, V1 = MT, V2 = MT, V3 = MT;
        if (act) {
            int rr = (c << 6) + lane;
            MT = ((const uint4*)meta)[rr];
            const uint4* vp = (const uint4*)(vict + (size_t)rr * VCAP);
            V0 = vp[0]; V1 = vp[1]; V2 = vp[2]; V3 = vp[3];
        }
        __syncthreads();                         // drains vmcnt: all loads landed

        if (act) {
            while (__hip_atomic_load(&turnv, __ATOMIC_ACQUIRE,
                                     __HIP_MEMORY_SCOPE_WORKGROUP) != (u32)c) {}

            int base = c << 6;
            u64 av = ((u64)alive[(base >> 5) + 1] << 32) | (u64)alive[base >> 5];
            u64 m = ((u64)MT.y << 32) | (u64)MT.x;
            int vc = min((int)MT.z, VCAP);
            u64 undec = av;
            u64 kept = 0ull;
            while (undec) {
                bool iam = (undec >> lane) & 1ull;
                bool bad = (m & kept) != 0ull;
                bool rdy = (m & undec) == 0ull;
                u64 newk = __ballot(iam && !bad && rdy);
                u64 newr = __ballot(iam && bad);
                u64 prog = newk | newr;
                if (prog == 0ull) { prog = undec & (~undec + 1ull); newk = prog; }
                kept |= newk;
                undec &= ~prog;
            }
            if (lane < 2) alive[(base >> 5) + lane] = (u32)(kept >> (lane * 32));

            int nv = ((kept >> lane) & 1ull) ? vc : 0;
#define VSC(wd, k) { \
    if ((int)(k) < nv)     { int tg = (int)((wd) & 0xFFFFu); atomicAnd(&alive[tg >> 5], ~(1u << (tg & 31))); } \
    if ((int)(k) + 1 < nv) { int tg = (int)((wd) >> 16);     atomicAnd(&alive[tg >> 5], ~(1u << (tg & 31))); } }
            if (__ballot(nv > 0)) {
                VSC(V0.x, 0)  VSC(V0.y, 2)  VSC(V0.z, 4)  VSC(V0.w, 6)
                VSC(V1.x, 8)  VSC(V1.y, 10) VSC(V1.z, 12) VSC(V1.w, 14)
                if (__ballot(nv > 16)) {
                    VSC(V2.x, 16) VSC(V2.y, 18) VSC(V2.z, 20) VSC(V2.w, 22)
                    VSC(V3.x, 24) VSC(V3.y, 26) VSC(V3.z, 28) VSC(V3.w, 30)
                }
                if (__ballot(nv > 32)) {
                    int r = base + lane;
                    for (int e = 32; e < nv; ++e) {
                        int tg = (int)vict[(size_t)r * VCAP + e];
                        atomicAnd(&alive[tg >> 5], ~(1u << (tg & 31)));
                    }
                }
            }
#undef VSC
            if (lane == 0)
                __hip_atomic_store(&turnv, (u32)(c + 1), __ATOMIC_RELEASE,
                                   __HIP_MEMORY_SCOPE_WORKGROUP);
        }
    }

    __syncthreads();
    if (tid < 512) keepf[tid] = alive[tid];
}

// ---------------------------------------------------------------------------
// K6: out[r] = sorted geometry * keep bit (rank space); rows >= M exact zeros.
// ---------------------------------------------------------------------------
__global__ void out_kernel(const float4* __restrict__ sbox, const u32* __restrict__ keepf,
                           const u32* __restrict__ Mptr, float4* __restrict__ out, int N) {
    int r = blockIdx.x * 256 + threadIdx.x;
    if (r >= N) return;
    int M = (int)*Mptr;
    if (r < M) {
        float k = (float)((keepf[r >> 5] >> (r & 31)) & 1u);
        float4 v = sbox[r];
        out[r] = make_float4(v.x * k, v.y * k, v.z * k, v.w * k);
    } else {
        out[r] = make_float4(0.0f, 0.0f, 0.0f, 0.0f);
    }
}

// ---------------------------------------------------------------------------
extern "C" void kernel_launch(void* const* d_in, const int* in_sizes, int n_in,
                              void* d_out, int out_size, void* d_ws, size_t ws_size,
                              hipStream_t stream) {
    const float* in = (const float*)d_in[0];
    int N = in_sizes[0] / 5;          // 16384

    char* ws = (char*)d_ws;
    size_t off = 0;
    // ---- zeroed region (one memset) ----
    u32* rankv   = (u32*)(ws + off); off += (size_t)N * 4;            // 64 KB
    u32* Mctr    = (u32*)(ws + off); off += 16;
    u32* bcnt    = (u32*)(ws + off); off += (size_t)NBIN * 4;         // 256 B
    u32* meta    = (u32*)(ws + off); off += (size_t)N * 16;           // 256 KB {m_lo,m_hi,vcnt,pad}
    size_t zbytes = off;
    // ---- non-zeroed ----
    float4* sbox  = (float4*)(ws + off); off += (size_t)N * 16;       // 256 KB
    float4* sboxg = (float4*)(ws + off); off += (size_t)N * 16;       // 256 KB
    u64* vkey    = (u64*)(ws + off);  off += (size_t)N * 8;           // 128 KB
    u16* vict    = (u16*)(ws + off);  off += (size_t)N * VCAP * 2;    // 6 MB (16B-aligned)
    u16* blist   = (u16*)(ws + off);  off += (size_t)NBIN * 256 * 2;  // 32 KB
    u16* grankg  = (u16*)(ws + off);  off += (size_t)N * 2;           // 32 KB
    u32* keepf   = (u32*)(ws + off);  off += 512 * 4;                 // 2 KB

    hipMemsetAsync(rankv, 0, zbytes, stream);

    compact_kernel<<<N / 256, 256, 0, stream>>>(in, Mctr, vkey, N);
    rankv_kernel<<<dim3(N / 256, N / 2048), 256, 0, stream>>>(vkey, Mctr, rankv, N);
    scatterv_kernel<<<N / 256, 256, 0, stream>>>(in, vkey, rankv, Mctr, sbox, bcnt, blist, N);
    bin_sort_kernel<<<NBIN, 256, 0, stream>>>(bcnt, blist, sbox, sboxg, grankg);
    mask_pm1_kernel<<<dim3(NBIN, 4), 256, 0, stream>>>(sboxg, grankg, bcnt, meta, vict);
    nms_seq_kernel<<<1, NWAVE * 64, 0, stream>>>(meta, vict, Mctr, keepf, N);
    out_kernel<<<N / 256, 256, 0, stream>>>(sbox, keepf, Mctr, (float4*)d_out, N);
}

// Round 7
// 240.886 us; speedup vs baseline: 1.1738x; 1.0223x over previous
//
#include <hip/hip_runtime.h>
#include <stdint.h>

typedef uint16_t u16;
typedef uint32_t u32;
typedef uint64_t u64;

#define CONF_THRESH 0.5f
#define PIOU_THRESH 0.5f
#define VCAP 192     // victim slots per box (in-degree <=128 verified R7/R8; out-degree symmetric)
#define NBIN 64      // fixed-width spatial bins (width 79.7; box width < 95 -> edges span <=1 bin)
#define NWAVE 8      // waves in NMS kernel: wave 0 consumes, waves 1-7 stage
#define CHW 1280     // u32 per chunk buffer: 256 meta + 1024 victims (5 KB)

// ---------------------------------------------------------------------------
// K0: compact valid boxes (conf > 0.5).
// ---------------------------------------------------------------------------
__global__ void compact_kernel(const float* __restrict__ in, u32* __restrict__ Mctr,
                               u64* __restrict__ vkey, int N) {
    int i = blockIdx.x * 256 + threadIdx.x;
    if (i >= N) return;
    float c = in[(size_t)i * 5];
    if (c > CONF_THRESH) {
        u32 slot = atomicAdd(Mctr, 1u);
        vkey[slot] = ((u64)__float_as_uint(c) << 32) | (u64)(0xFFFFFFFFu - (u32)i);
    }
}

// ---------------------------------------------------------------------------
// K1: rank among valid via O(M^2) counting (key = conf_bits<<32 | ~idx).
// ---------------------------------------------------------------------------
__global__ void rankv_kernel(const u64* __restrict__ vkey, const u32* __restrict__ Mptr,
                             u32* __restrict__ rankv, int N) {
    __shared__ u64 keys[2048];
    int M = (int)*Mptr;
    int t = threadIdx.x;
    int i = blockIdx.x * 256 + t;
    int j0 = blockIdx.y * 2048;
    if (j0 >= M) return;
    if (blockIdx.x * 256 >= M) return;           // whole block inactive: skip staging
    for (int k = t; k < 2048; k += 256) {
        int j = j0 + k;
        keys[k] = (j < M) ? vkey[j] : 0ull;
    }
    __syncthreads();
    if (i >= M) return;
    u64 my = vkey[i];
    int cnt = 0;
    for (int k = 0; k < 2048; ++k) cnt += (keys[k] > my) ? 1 : 0;
    if (cnt) atomicAdd(&rankv[i], (u32)cnt);
}

// ---------------------------------------------------------------------------
// K2: scatter valid boxes into rank order + spatial bin append.
// ---------------------------------------------------------------------------
__global__ void scatterv_kernel(const float* __restrict__ in, const u64* __restrict__ vkey,
                                const u32* __restrict__ rankv, const u32* __restrict__ Mptr,
                                float4* __restrict__ sbox, u32* __restrict__ bcnt,
                                u16* __restrict__ blist, int N) {
    int s = blockIdx.x * 256 + threadIdx.x;
    int M = (int)*Mptr;
    if (s >= M) return;
    u32 idx = 0xFFFFFFFFu - (u32)(vkey[s] & 0xFFFFFFFFull);
    u32 r = rankv[s];
    const float* p = in + (size_t)idx * 5;
    float st = p[1], en = p[2], pk = p[3], h = p[4];
    sbox[r] = make_float4(st, en, pk, h);
    int bin = min(NBIN - 1, max(0, (int)(st * ((float)NBIN / 5100.0f))));
    u32 slot = atomicAdd(&bcnt[bin], 1u);
    if (slot < 256) blist[bin * 256 + slot] = (u16)r;
}

// ---------------------------------------------------------------------------
// K3: within-bin rank sort -> gidx-ordered geometry (sboxg) and rank (grankg;
// 0xFFFF marks empty slots). Spatial index for K4.
// ---------------------------------------------------------------------------
__global__ void bin_sort_kernel(const u32* __restrict__ bcnt, const u16* __restrict__ blist,
                                const float4* __restrict__ sbox,
                                float4* __restrict__ sboxg, u16* __restrict__ grankg) {
    __shared__ u16 rl[256];
    int bin = blockIdx.x, t = threadIdx.x;
    int n = min((int)bcnt[bin], 256);
    rl[t] = (t < n) ? blist[bin * 256 + t] : (u16)0xFFFF;
    __syncthreads();
    if (t < n) {
        u16 my = rl[t];
        int lr = 0;
        for (int q = 0; q < 256; ++q) lr += (rl[q] < my) ? 1 : 0;
        int g = bin * 256 + lr;
        grankg[g] = my;
        sboxg[g] = sbox[my];
    } else {
        grankg[bin * 256 + t] = (u16)0xFFFF;
    }
}

// ---------------------------------------------------------------------------
// K4: suppression edges, +-1-bin window (provably sufficient). Edge ri->rj
// (ri < rj in rank): same 64-rank chunk -> in-chunk mask bit in meta[rj];
// cross-chunk -> victim-list append on ri. meta[r] = {m_lo, m_hi, vcnt, pad}.
// ---------------------------------------------------------------------------
__global__ void mask_pm1_kernel(const float4* __restrict__ sboxg, const u16* __restrict__ grankg,
                                const u32* __restrict__ bcnt,
                                u32* __restrict__ meta, u16* __restrict__ vict) {
#pragma clang fp contract(off)
    __shared__ float4 cb[192];
    __shared__ u16 cr[192];
    int b = (int)blockIdx.x, s = (int)blockIdx.y, t = threadIdx.x;
    int w0 = (b - 1) * 256 + s * 192;            // window slice start (gidx)
    if (t < 192) {
        int g = w0 + t;
        bool ok = (g >= 0) && (g < NBIN * 256);
        cr[t] = ok ? grankg[g] : (u16)0xFFFF;
        cb[t] = ok ? sboxg[g] : make_float4(0.0f, 0.0f, 0.0f, 0.0f);
    }
    __syncthreads();
    int nb = min((int)bcnt[b], 256);
    int l = t;
    if (l >= nb) return;
    int g = b * 256 + l;
    int rj = (int)grankg[g];
    float4 bj = sboxg[g];
    float areaj = (bj.y - bj.x) * bj.w;
    for (int q = 0; q < 192; ++q) {
        int ri = (int)cr[q];
        if (ri >= rj) continue;                  // skips empties (0xFFFF) and self
        float4 bi = cb[q];
        float inter_start = fmaxf(bi.x, bj.x);
        float inter_end   = fminf(bi.y, bj.y);
        float inter_len   = fmaxf(inter_end - inter_start, 0.0f);
        float inter_h     = fminf(bi.w, bj.w);
        float inter_area  = inter_len * inter_h;
        float areai       = (bi.y - bi.x) * bi.w;
        float union_area  = areai + areaj - inter_area;
        float iou         = inter_area / union_area;
        float peak_dist   = fabsf(bi.z - bj.z);
        float union_start = fminf(bi.x, bj.x);
        float union_end   = fmaxf(bi.y, bj.y);
        float union_dist  = fabsf(union_end - union_start);
        float piou        = iou - peak_dist / union_dist;
        if (piou > PIOU_THRESH) {
            if ((ri >> 6) == (rj >> 6)) {
                atomicOr(&meta[rj * 4 + ((ri >> 5) & 1)], 1u << (ri & 31));
            } else {
                u32 slot = atomicAdd(&meta[ri * 4 + 2], 1u);
                if (slot < VCAP) vict[(size_t)ri * VCAP + slot] = (u16)rj;
            }
        }
    }
}

// ---------------------------------------------------------------------------
// K5: EXACT greedy NMS, producer/consumer LDS staging (no asm, no spins).
// Waves 1-7 stage round rd+1's 8 chunks (meta + 32 victims each) into a
// double-buffered LDS area via plain loads + ds_write: a global load feeding
// a ds_write before __syncthreads CANNOT be sunk past the barrier (the LDS
// write must be visible to other waves) -- so prefetch placement is
// structurally guaranteed, unlike R2/R6 where the compiler sank the loads.
// Wave 0 alone processes the current round's chunks sequentially from LDS:
// alive read -> proven ballot fixpoint -> victim atomicAnd scatter. No turn
// counter, no spin; one uniform barrier per round; deadlock impossible.
// Fixpoint masks are lower-triangular by construction; forced-progress guard
// kept as hang insurance (dead code on valid data).
// ---------------------------------------------------------------------------
__global__ void __launch_bounds__(NWAVE * 64) nms_seq_kernel(
        const u32* __restrict__ meta, const u16* __restrict__ vict,
        const u32* __restrict__ Mptr, u32* __restrict__ keepf, int N) {
    __shared__ u32 alive[512];                   // 16384 bits, rank space
    __shared__ u32 sbuf[2][NWAVE][CHW];          // 80 KB double-buffered stage
    int tid = threadIdx.x;
    int w = tid >> 6, lane = tid & 63;
    int M = (int)*Mptr;
    {
        int lo = tid * 32;
        alive[tid] = (M >= lo + 32) ? 0xFFFFFFFFu : ((M <= lo) ? 0u : ((1u << (M - lo)) - 1u));
    }
    int nchunk = (M + 63) >> 6;
    int nround = (nchunk + NWAVE - 1) / NWAVE;
    __syncthreads();
    if (nchunk == 0) {
        keepf[tid] = 0u;
        return;
    }

#define STAGE(c, pb, k) { \
    int rr = ((c) << 6) + lane; \
    uint4 MT = ((const uint4*)meta)[rr]; \
    const uint4* vp = (const uint4*)(vict + (size_t)rr * VCAP); \
    uint4 V0 = vp[0], V1 = vp[1], V2 = vp[2], V3 = vp[3]; \
    u32* sb = &sbuf[pb][k][0]; \
    ((uint4*)sb)[lane] = MT; \
    uint4* vd = (uint4*)(sb + 256) + lane * 4; \
    vd[0] = V0; vd[1] = V1; vd[2] = V2; vd[3] = V3; }

#define VSC(wd, k) { \
    if ((int)(k) < nv)     { int tg = (int)((wd) & 0xFFFFu); atomicAnd(&alive[tg >> 5], ~(1u << (tg & 31))); } \
    if ((int)(k) + 1 < nv) { int tg = (int)((wd) >> 16);     atomicAnd(&alive[tg >> 5], ~(1u << (tg & 31))); } }

    // prologue: waves 1-7 stage round 0 into buffer 0 (wave 1 takes k=0 and 7)
    if (w >= 1) {
        for (int k = w - 1; k < NWAVE; k += 7) {
            int c = k;
            if (c < nchunk) STAGE(c, 0, k)
        }
    }
    __syncthreads();

    for (int rd = 0; rd < nround; ++rd) {
        int pb = rd & 1;
        if (w >= 1) {
            // stage round rd+1 into the other buffer
            int b2 = (rd + 1) * NWAVE;
            for (int k = w - 1; k < NWAVE; k += 7) {
                int c = b2 + k;
                if (c < nchunk) STAGE(c, pb ^ 1, k)
            }
        } else {
            // wave 0: process this round's chunks in rank order from LDS
            for (int k = 0; k < NWAVE; ++k) {
                int c = rd * NWAVE + k;
                if (c >= nchunk) break;          // uniform within wave 0
                int base = c << 6;
                const u32* sb = &sbuf[pb][k][0];
                uint4 MT = ((const uint4*)sb)[lane];
                u64 m = ((u64)MT.y << 32) | (u64)MT.x;
                int vc = min((int)MT.z, VCAP);
                u64 av = ((u64)alive[(base >> 5) + 1] << 32) | (u64)alive[base >> 5];
                u64 undec = av;
                u64 kept = 0ull;
                while (undec) {
                    bool iam = (undec >> lane) & 1ull;
                    bool bad = (m & kept) != 0ull;
                    bool rdy = (m & undec) == 0ull;
                    u64 newk = __ballot(iam && !bad && rdy);
                    u64 newr = __ballot(iam && bad);
                    u64 prog = newk | newr;
                    if (prog == 0ull) { prog = undec & (~undec + 1ull); newk = prog; }
                    kept |= newk;
                    undec &= ~prog;
                }
                if (lane < 2) alive[(base >> 5) + lane] = (u32)(kept >> (lane * 32));

                int nv = ((kept >> lane) & 1ull) ? vc : 0;
                if (__ballot(nv > 0)) {
                    const uint4* vd = (const uint4*)(sb + 256) + lane * 4;
                    uint4 V0 = vd[0], V1 = vd[1];
                    VSC(V0.x, 0)  VSC(V0.y, 2)  VSC(V0.z, 4)  VSC(V0.w, 6)
                    VSC(V1.x, 8)  VSC(V1.y, 10) VSC(V1.z, 12) VSC(V1.w, 14)
                    if (__ballot(nv > 16)) {
                        uint4 V2 = vd[2], V3 = vd[3];
                        VSC(V2.x, 16) VSC(V2.y, 18) VSC(V2.z, 20) VSC(V2.w, 22)
                        VSC(V3.x, 24) VSC(V3.y, 26) VSC(V3.z, 28) VSC(V3.w, 30)
                    }
                    if (__ballot(nv > 32)) {
                        int r = base + lane;
                        for (int e = 32; e < nv; ++e) {
                            int tg = (int)vict[(size_t)r * VCAP + e];
                            atomicAnd(&alive[tg >> 5], ~(1u << (tg & 31)));
                        }
                    }
                }
            }
        }
        __syncthreads();                         // staging done + buffer handoff
    }

    keepf[tid] = alive[tid];
#undef STAGE
#undef VSC
}

// ---------------------------------------------------------------------------
// K6: out[r] = sorted geometry * keep bit (rank space); rows >= M exact zeros.
// ---------------------------------------------------------------------------
__global__ void out_kernel(const float4* __restrict__ sbox, const u32* __restrict__ keepf,
                           const u32* __restrict__ Mptr, float4* __restrict__ out, int N) {
    int r = blockIdx.x * 256 + threadIdx.x;
    if (r >= N) return;
    int M = (int)*Mptr;
    if (r < M) {
        float k = (float)((keepf[r >> 5] >> (r & 31)) & 1u);
        float4 v = sbox[r];
        out[r] = make_float4(v.x * k, v.y * k, v.z * k, v.w * k);
    } else {
        out[r] = make_float4(0.0f, 0.0f, 0.0f, 0.0f);
    }
}

// ---------------------------------------------------------------------------
extern "C" void kernel_launch(void* const* d_in, const int* in_sizes, int n_in,
                              void* d_out, int out_size, void* d_ws, size_t ws_size,
                              hipStream_t stream) {
    const float* in = (const float*)d_in[0];
    int N = in_sizes[0] / 5;          // 16384

    char* ws = (char*)d_ws;
    size_t off = 0;
    // ---- zeroed region (one memset) ----
    u32* rankv   = (u32*)(ws + off); off += (size_t)N * 4;            // 64 KB
    u32* Mctr    = (u32*)(ws + off); off += 16;
    u32* bcnt    = (u32*)(ws + off); off += (size_t)NBIN * 4;         // 256 B
    u32* meta    = (u32*)(ws + off); off += (size_t)N * 16;           // 256 KB {m_lo,m_hi,vcnt,pad}
    size_t zbytes = off;
    // ---- non-zeroed ----
    float4* sbox  = (float4*)(ws + off); off += (size_t)N * 16;       // 256 KB
    float4* sboxg = (float4*)(ws + off); off += (size_t)N * 16;       // 256 KB
    u64* vkey    = (u64*)(ws + off);  off += (size_t)N * 8;           // 128 KB
    u16* vict    = (u16*)(ws + off);  off += (size_t)N * VCAP * 2;    // 6 MB (16B-aligned)
    u16* blist   = (u16*)(ws + off);  off += (size_t)NBIN * 256 * 2;  // 32 KB
    u16* grankg  = (u16*)(ws + off);  off += (size_t)N * 2;           // 32 KB
    u32* keepf   = (u32*)(ws + off);  off += 512 * 4;                 // 2 KB

    hipMemsetAsync(rankv, 0, zbytes, stream);

    compact_kernel<<<N / 256, 256, 0, stream>>>(in, Mctr, vkey, N);
    rankv_kernel<<<dim3(N / 256, N / 2048), 256, 0, stream>>>(vkey, Mctr, rankv, N);
    scatterv_kernel<<<N / 256, 256, 0, stream>>>(in, vkey, rankv, Mctr, sbox, bcnt, blist, N);
    bin_sort_kernel<<<NBIN, 256, 0, stream>>>(bcnt, blist, sbox, sboxg, grankg);
    mask_pm1_kernel<<<dim3(NBIN, 4), 256, 0, stream>>>(sboxg, grankg, bcnt, meta, vict);
    nms_seq_kernel<<<1, NWAVE * 64, 0, stream>>>(meta, vict, Mctr, keepf, N);
    out_kernel<<<N / 256, 256, 0, stream>>>(sbox, keepf, Mctr, (float4*)d_out, N);
}